// Round 8
// baseline (299.959 us; speedup 1.0000x reference)
//
#include <hip/hip_runtime.h>
#include <stdint.h>

// MHA forward: B=4, T=2048, C=1024, H=16, HD=64.
// Pipeline: cast/transpose to bf16 -> QKV GEMM (MFMA, BK=64, swizzled LDS,
//              operand-swapped v_perm epilogue, XCD m-slabs)
//           -> causal flash attention (block-staged LDS tiles, swizzled,
//              S^T shuffle-free softmax, band-paired uniform blocks)
//           -> proj GEMM (same GEMM, fp32 float4 out).

typedef __attribute__((ext_vector_type(8))) short bf16x8;
typedef __attribute__((ext_vector_type(4))) float f32x4;

#define MFMA(a, b, c) __builtin_amdgcn_mfma_f32_16x16x32_bf16((a), (b), (c), 0, 0, 0)

#define NB 4
#define NT 2048
#define NC 1024
#define NH 16
#define HD 64
#define SCALE_Q 0.18033688011112042f  // 1/sqrt(64) * log2(e): softmax in base-2

__device__ __forceinline__ short f2bf(float f) {
  union { float fv; uint32_t u; } v; v.fv = f;
  uint32_t u = v.u;
  uint32_t r = (u + 0x7fffu + ((u >> 16) & 1u)) >> 16;
  return (short)(r & 0xffffu);
}

// pack two fp32 -> bf16 pair (round-half-away) in 3 VALU ops via v_perm_b32.
// v_perm byte vector = {S0 = bytes 7..4, S1 = bytes 3..0}; sel 0x07060302
// -> D = (S0.hi16 << 16) | S1.hi16. Call (b,a): low16 = bf16(a) = elem 0.
__device__ __forceinline__ uint32_t pkbf(float a, float b) {
  union { float f; uint32_t u; } ua, ub; ua.f = a; ub.f = b;
  return __builtin_amdgcn_perm(ub.u + 0x8000u, ua.u + 0x8000u, 0x07060302u);
}

__device__ __forceinline__ void gl_lds16(const void* g, void* l) {
  __builtin_amdgcn_global_load_lds(
      (const __attribute__((address_space(1))) void*)g,
      (__attribute__((address_space(3))) void*)l, 16, 0, 0);
}

// ---------------- pre-pass kernels ----------------

__global__ void cast_f32_bf16(const float* __restrict__ src, short* __restrict__ dst, int n8) {
  int i = blockIdx.x * blockDim.x + threadIdx.x;
  if (i >= n8) return;
  const float4* s4 = (const float4*)src;
  float4 a = s4[2 * i], b = s4[2 * i + 1];
  bf16x8 o;
  o[0] = f2bf(a.x); o[1] = f2bf(a.y); o[2] = f2bf(a.z); o[3] = f2bf(a.w);
  o[4] = f2bf(b.x); o[5] = f2bf(b.y); o[6] = f2bf(b.z); o[7] = f2bf(b.w);
  *(bf16x8*)&dst[8 * i] = o;
}

// src [R][Cc] fp32 (row-major) -> dst [Cc][R] bf16 (row-major), i.e. B^T layout.
__global__ void transpose_cast(const float* __restrict__ src, short* __restrict__ dst,
                               int R, int Cc) {
  __shared__ float tile[64][65];
  int tid = threadIdx.x;
  int c0 = blockIdx.x * 64;
  int r0 = blockIdx.y * 64;
  int lr = tid >> 4;           // 0..15
  int lc = (tid & 15) * 4;     // 0..60
#pragma unroll
  for (int i = 0; i < 4; i++) {
    int rr = lr + i * 16;
    float4 v = *(const float4*)&src[(size_t)(r0 + rr) * Cc + c0 + lc];
    tile[rr][lc + 0] = v.x; tile[rr][lc + 1] = v.y;
    tile[rr][lc + 2] = v.z; tile[rr][lc + 3] = v.w;
  }
  __syncthreads();
  int oc = tid >> 2;           // dst row (= src col) 0..63
  int seg = (tid & 3) * 16;    // dst col segment
  bf16x8 o0, o1;
#pragma unroll
  for (int u = 0; u < 8; u++) o0[u] = f2bf(tile[seg + u][oc]);
#pragma unroll
  for (int u = 0; u < 8; u++) o1[u] = f2bf(tile[seg + 8 + u][oc]);
  size_t base = (size_t)(c0 + oc) * R + r0 + seg;
  *(bf16x8*)&dst[base] = o0;
  *(bf16x8*)&dst[base + 8] = o1;
}

// ---------------- GEMM: C[M,N] = A[M,K] @ B[K,N], B given transposed [N,K] ----------------
// M fixed 8192 (64 m-tiles). 128x128 tile, BK=64, 256 threads, 4x4 MFMA/wave.
// XOR chunk swizzle on the staging global side -> conflict-free b128 frag reads.
// XCD m-slab: bid&7 = XCD owns 8 consecutive m-tiles (A slab stays in its L2).
// Operand swap (uniform per block): q/k/proj use MFMA(B,A) -> acc regs are
// contiguous in the output minor dim -> b64 / float4 stores.
// mode 0: QKV scatter (bf16 q/k/vT); mode 1: fp32 out.

__global__ __launch_bounds__(256, 2)
void gemm_bt_kernel(const short* __restrict__ A, const short* __restrict__ BT,
                    int N, int K, int nbx, int mode,
                    short* __restrict__ q, short* __restrict__ kk, short* __restrict__ vT,
                    float* __restrict__ f_out) {
  __shared__ short sA[128 * 64];
  __shared__ short sB[128 * 64];
  const int tid = threadIdx.x;
  const int lane = tid & 63;
  const int w = tid >> 6;
  const int quad = lane >> 4;
  const int r = lane & 15;

  const int bid = blockIdx.x;
  const int xcd = bid & 7;
  const int local = bid >> 3;
  const int mloc = local / nbx, nloc = local - mloc * nbx;
  const int bm0 = (xcd * 8 + mloc) * 128;   // 64 m-tiles, 8 per XCD
  const int bn0 = nloc * 128;

  const int wm = (w >> 1) * 64;
  const int wn = (w & 1) * 64;
  const int sel = (mode == 0) ? (bn0 >> 10) : 3;   // 0=q,1=k,2=v,3=proj
  const bool swapped = (sel != 2);

  f32x4 acc[4][4];
#pragma unroll
  for (int i = 0; i < 4; i++)
#pragma unroll
    for (int j = 0; j < 4; j++) acc[i][j] = (f32x4){0.f, 0.f, 0.f, 0.f};

  for (int kb = 0; kb < K; kb += 64) {
    __syncthreads();
#pragma unroll
    for (int j2 = 0; j2 < 4; j2++) {
      int idx = (w * 4 + j2) * 64 + lane;    // 1024 chunks of 16B per tile
      int row = idx >> 3, ch = idx & 7;
      int g = ch ^ (row & 7);                // global-side swizzle
      gl_lds16(A + (size_t)(bm0 + row) * K + kb + g * 8, (char*)sA + idx * 16);
      gl_lds16(BT + (size_t)(bn0 + row) * K + kb + g * 8, (char*)sB + idx * 16);
    }
    __syncthreads();
#pragma unroll
    for (int c = 0; c < 2; c++) {
      bf16x8 af[4], bfr[4];
#pragma unroll
      for (int i = 0; i < 4; i++) {
        const int sw = ((c << 2) + quad) ^ (r & 7);
        af[i]  = *(const bf16x8*)&sA[(wm + i * 16 + r) * 64 + sw * 8];
        bfr[i] = *(const bf16x8*)&sB[(wn + i * 16 + r) * 64 + sw * 8];
      }
      if (swapped) {
#pragma unroll
        for (int i = 0; i < 4; i++)
#pragma unroll
          for (int j = 0; j < 4; j++)
            acc[i][j] = MFMA(bfr[j], af[i], acc[i][j]);   // C^T tile
      } else {
#pragma unroll
        for (int i = 0; i < 4; i++)
#pragma unroll
          for (int j = 0; j < 4; j++)
            acc[i][j] = MFMA(af[i], bfr[j], acc[i][j]);
      }
    }
  }

  if (mode == 1) {
    // swapped: row=quad*4+reg = n (contiguous), col=r = m -> float4 stores
#pragma unroll
    for (int i = 0; i < 4; i++) {
      const int m = bm0 + wm + i * 16 + r;
#pragma unroll
      for (int j = 0; j < 4; j++) {
        const int nf = bn0 + wn + j * 16 + quad * 4;
        *(f32x4*)&f_out[(size_t)m * N + nf] = acc[i][j];
      }
    }
  } else if (sel == 2) {
    // v, unswapped: row=quad*4+reg = token t (contiguous), col=r -> n
    // vT stored [B,H,HD,T]: regs = consecutive t -> b64 store
#pragma unroll
    for (int j = 0; j < 4; j++) {
      const int n = bn0 + wn + j * 16 + r;
      const int d = n & 63, h = (n & 1023) >> 6;
#pragma unroll
      for (int i = 0; i < 4; i++) {
        const int t0 = bm0 + wm + i * 16 + quad * 4;
        const int bh = (t0 >> 11) * NH + h;
        uint2 pk = make_uint2(pkbf(acc[i][j][0], acc[i][j][1]),
                              pkbf(acc[i][j][2], acc[i][j][3]));
        *(uint2*)&vT[((size_t)bh * HD + d) * NT + (t0 & 2047)] = pk;
      }
    }
  } else {
    // q/k, swapped: regs = consecutive d -> b64 store per (i,j)
    short* dst = (sel == 0) ? q : kk;
    const float scl = (sel == 0) ? SCALE_Q : 1.0f;
#pragma unroll
    for (int i = 0; i < 4; i++) {
      const int t = bm0 + wm + i * 16 + r;
      const int bb = (t >> 11) * NH;
      const int tt = t & 2047;
#pragma unroll
      for (int j = 0; j < 4; j++) {
        const int nf = bn0 + wn + j * 16 + quad * 4;
        const int rem = nf & 1023, h = rem >> 6, d0 = rem & 63;
        uint2 pk = make_uint2(pkbf(acc[i][j][0] * scl, acc[i][j][1] * scl),
                              pkbf(acc[i][j][2] * scl, acc[i][j][3] * scl));
        *(uint2*)&dst[((size_t)(bb + h) * NT + tt) * HD + d0] = pk;
      }
    }
  }
}

// ---------------- causal flash attention (block-staged, shuffle-free) ----------------
// Band = 128 q-rows. Each block processes bands (15-pr, pr) of one head:
// (16-pr) + (pr+1) = 17 KV tiles per block -> uniform grid of 512 blocks
// (2/CU resident, zero tail). K[128x64], V^T[64x128] staged via
// global_load_lds w16 + XOR swizzle. S^T = K @ Q^T keeps softmax lane-local;
// row sums via MFMA vs ones; P packed with v_perm (3 VALU/pair).
// P buffer: ONE 16x136 strip per wave, strips processed sequentially
// (same-wave LDS ordering + lgkmcnt(0) makes reuse safe; stride 136 >= 128!).
// Grid: XCD-local heads (n&7 = XCD).

__device__ __forceinline__ void attn_band(
    const short* __restrict__ Qb, const short* __restrict__ Kb,
    const short* __restrict__ VTb, short* __restrict__ Og,
    short* __restrict__ sK, short* __restrict__ sV, short* __restrict__ sPw,
    const int band, const int bh, const int w, const int lane) {
  const int quad = lane >> 4;
  const int r = lane & 15;
  const int q0 = band * 128 + w * 32;    // wave's 32 q-rows (2 strips)

  // Q as B-operand (n = q-row = lane&15, k contiguous d)
  bf16x8 bQ[2][2];
#pragma unroll
  for (int mi = 0; mi < 2; mi++) {
    const size_t qrow = ((size_t)q0 + mi * 16 + r) * HD;
    bQ[mi][0] = *(const bf16x8*)&Qb[qrow + quad * 8];
    bQ[mi][1] = *(const bf16x8*)&Qb[qrow + 32 + quad * 8];
  }
  bf16x8 vone;
#pragma unroll
  for (int u = 0; u < 8; u++) vone[u] = (short)0x3F80;  // bf16 1.0

  f32x4 acc[2][4];
  f32x4 lacc[2];
#pragma unroll
  for (int mi = 0; mi < 2; mi++) {
    lacc[mi] = (f32x4){0.f, 0.f, 0.f, 0.f};
#pragma unroll
    for (int dt = 0; dt < 4; dt++) acc[mi][dt] = (f32x4){0.f, 0.f, 0.f, 0.f};
  }

  for (int kt = 0; kt <= band; kt++) {
    const int kv0 = kt * 128;
    const bool diag = (kt == band);
    __syncthreads();                     // prior-tile LDS consumers done
#pragma unroll
    for (int j = 0; j < 4; j++) {
      int idx = (w * 4 + j) * 64 + lane; // 1024 chunks of 16B per tile
      int krow = idx >> 3, kch = idx & 7;
      int kg = kch ^ (krow & 7);         // global-side swizzle
      gl_lds16(Kb + (size_t)(kv0 + krow) * HD + kg * 8, (char*)sK + idx * 16);
      int vrow = idx >> 4, vch = idx & 15;
      int vg = (vch & 8) | ((vch ^ vrow) & 7);
      gl_lds16(VTb + (size_t)vrow * NT + kv0 + vg * 8, (char*)sV + idx * 16);
    }
    __syncthreads();                     // drains vmcnt(0): tiles landed

    // V fragments hoisted once per tile, reused by both strips
    bf16x8 vf[4][4];
#pragma unroll
    for (int dt = 0; dt < 4; dt++)
#pragma unroll
      for (int c = 0; c < 4; c++) {
        int ch = quad + 4 * c;
        int sw = (ch & 8) | ((ch ^ (r & 7)) & 7);
        vf[dt][c] = *(const bf16x8*)&sV[(dt * 16 + r) * 128 + sw * 8];
      }

#pragma unroll
    for (int mi = 0; mi < 2; mi++) {
      const int nts = diag ? (w * 2 + mi + 1) : 8;   // live kv subtiles
#pragma unroll
      for (int nt = 0; nt < 8; nt++) {
        uint2 pk = make_uint2(0u, 0u);
        if (nt < nts) {                  // wave-uniform
          const int krow = nt * 16 + r;
          const int sw0 = quad ^ (r & 7);
          bf16x8 k0 = *(const bf16x8*)&sK[krow * 64 + sw0 * 8];
          bf16x8 k1 = *(const bf16x8*)&sK[krow * 64 + (sw0 ^ 4) * 8];
          f32x4 st = (f32x4){0.f, 0.f, 0.f, 0.f};
          st = MFMA(k0, bQ[mi][0], st);
          st = MFMA(k1, bQ[mi][1], st);
          if (diag && nt == nts - 1) {   // only the straddling subtile
            const int kvb = kv0 + nt * 16 + quad * 4;
            const int qg = q0 + mi * 16 + r;
#pragma unroll
            for (int reg = 0; reg < 4; reg++)
              if (kvb + reg > qg) st[reg] = -1e30f;
          }
          pk.x = pkbf(__builtin_amdgcn_exp2f(st[0]), __builtin_amdgcn_exp2f(st[1]));
          pk.y = pkbf(__builtin_amdgcn_exp2f(st[2]), __builtin_amdgcn_exp2f(st[3]));
        }
        *(uint2*)&sPw[r * 136 + nt * 16 + quad * 4] = pk;
      }
      __builtin_amdgcn_s_waitcnt(0xc07f);  // lgkmcnt(0); same-wave, no barrier
      bf16x8 aP[4];
#pragma unroll
      for (int c = 0; c < 4; c++)
        aP[c] = *(const bf16x8*)&sPw[r * 136 + c * 32 + quad * 8];
#pragma unroll
      for (int c = 0; c < 4; c++)
        lacc[mi] = MFMA(aP[c], vone, lacc[mi]);     // l += P @ 1
#pragma unroll
      for (int dt = 0; dt < 4; dt++)
#pragma unroll
        for (int c = 0; c < 4; c++)
          acc[mi][dt] = MFMA(aP[c], vf[dt][c], acc[mi][dt]);
    }
  }

  // epilogue: O/l, C-layout (row=quad*4+reg=q-row, col=r); token-major bf16 out
  const int b = bh >> 4, h = bh & 15;
#pragma unroll
  for (int mi = 0; mi < 2; mi++)
#pragma unroll
    for (int reg = 0; reg < 4; reg++) {
      const int trow = q0 + mi * 16 + quad * 4 + reg;
      const float inv = 1.0f / lacc[mi][reg];
      const size_t base = ((size_t)(b * NT + trow)) * NC + h * HD;
#pragma unroll
      for (int dt = 0; dt < 4; dt++)
        Og[base + dt * 16 + r] = f2bf(acc[mi][dt][reg] * inv);
    }
}

__global__ __launch_bounds__(256, 3)
void attn_kernel(const short* __restrict__ Q, const short* __restrict__ Kg,
                 const short* __restrict__ VT, short* __restrict__ Og) {
  __shared__ short sK[128 * 64];       // [kv][d], chunk-swizzled
  __shared__ short sV[64 * 128];       // [d][kv], chunk-swizzled
  __shared__ short sP[4][16 * 136];    // per-wave P strip, stride 136 (>=128+pad)
  const int tid = threadIdx.x;
  const int lane = tid & 63;
  const int w = tid >> 6;

  const int n = blockIdx.x;              // 0..511
  const int xcd = n & 7;
  const int slot = n >> 3;               // 0..63
  const int bh = xcd * 8 + (slot & 7);   // 8 heads per XCD
  const int pr = slot >> 3;              // 0..7 -> bands (15-pr, pr): 17 tiles

  const short* Qb  = Q  + (size_t)bh * NT * HD;
  const short* Kb  = Kg + (size_t)bh * NT * HD;
  const short* VTb = VT + (size_t)bh * HD * NT;

  attn_band(Qb, Kb, VTb, Og, sK, sV, &sP[w][0], 15 - pr, bh, w, lane);
  attn_band(Qb, Kb, VTb, Og, sK, sV, &sP[w][0], pr, bh, w, lane);
}

// ---------------- launch ----------------

extern "C" void kernel_launch(void* const* d_in, const int* in_sizes, int n_in,
                              void* d_out, int out_size, void* d_ws, size_t ws_size,
                              hipStream_t stream) {
  const float* x     = (const float*)d_in[0];   // [B,T,C] fp32
  const float* wqkv  = (const float*)d_in[1];   // [C,3C] fp32
  const float* wproj = (const float*)d_in[2];   // [C,C] fp32
  float* out = (float*)d_out;                   // [B,T,C] fp32

  // workspace layout (bytes): 88 MB total
  char* ws = (char*)d_ws;
  short* xb  = (short*)(ws + 0);          // x bf16        16,777,216 B
  short* wqT = (short*)(ws + 16777216);   // w_qkv^T bf16   6,291,456 B
  short* wpT = (short*)(ws + 23068672);   // w_proj^T bf16  2,097,152 B
  short* q   = (short*)(ws + 25165824);   // [B,H,T,HD]    16,777,216 B
  short* kk  = (short*)(ws + 41943040);   // [B,H,T,HD]    16,777,216 B
  short* vT  = (short*)(ws + 58720256);   // [B,H,HD,T]    16,777,216 B
  short* att = (short*)(ws + 75497472);   // [B*T, C] bf16 16,777,216 B

  cast_f32_bf16<<<4096, 256, 0, stream>>>(x, xb, (NB * NT * NC) / 8);
  transpose_cast<<<dim3(48, 16), 256, 0, stream>>>(wqkv, wqT, NC, 3 * NC);
  transpose_cast<<<dim3(16, 16), 256, 0, stream>>>(wproj, wpT, NC, NC);
  // qkv = xb @ wqkv  -> scatter to q/k/vT   (1536 blocks: 8 XCD x 8m x 24n)
  gemm_bt_kernel<<<1536, 256, 0, stream>>>(xb, wqT, 3 * NC, NC, 24, 0, q, kk, vT, nullptr);
  // attention (512 uniform blocks: 8 XCD x 8 heads x 8 band-pairs)
  attn_kernel<<<512, 256, 0, stream>>>(q, kk, vT, att);
  // out = att @ wproj  (512 blocks: 8 XCD x 8m x 8n)
  gemm_bt_kernel<<<512, 256, 0, stream>>>(att, wpT, NC, NC, 8, 1, nullptr, nullptr, nullptr, out);
}

// Round 9
// 274.711 us; speedup vs baseline: 1.0919x; 1.0919x over previous
//
#include <hip/hip_runtime.h>
#include <stdint.h>

// MHA forward: B=4, T=2048, C=1024, H=16, HD=64.
// Pipeline: cast/transpose to bf16 -> QKV GEMM (MFMA, BK=64, swizzled LDS,
//              operand-swapped v_perm epilogue, XCD m-slabs)
//           -> causal flash attention (block-staged LDS tiles, swizzled,
//              S^T shuffle-free softmax, 1024-block heavy-first grid,
//              nt-outer shared K fragments)
//           -> proj GEMM (same GEMM, fp32 float4 out).

typedef __attribute__((ext_vector_type(8))) short bf16x8;
typedef __attribute__((ext_vector_type(4))) float f32x4;

#define MFMA(a, b, c) __builtin_amdgcn_mfma_f32_16x16x32_bf16((a), (b), (c), 0, 0, 0)

#define NB 4
#define NT 2048
#define NC 1024
#define NH 16
#define HD 64
#define SCALE_Q 0.18033688011112042f  // 1/sqrt(64) * log2(e): softmax in base-2

__device__ __forceinline__ short f2bf(float f) {
  union { float fv; uint32_t u; } v; v.fv = f;
  uint32_t u = v.u;
  uint32_t r = (u + 0x7fffu + ((u >> 16) & 1u)) >> 16;
  return (short)(r & 0xffffu);
}

// pack two fp32 -> bf16 pair (round-half-away) in 3 VALU ops via v_perm_b32.
// v_perm byte vector = {S0 = bytes 7..4, S1 = bytes 3..0}; sel 0x07060302
// -> D = (S0.hi16 << 16) | S1.hi16. Call (b,a): low16 = bf16(a) = elem 0.
__device__ __forceinline__ uint32_t pkbf(float a, float b) {
  union { float f; uint32_t u; } ua, ub; ua.f = a; ub.f = b;
  return __builtin_amdgcn_perm(ub.u + 0x8000u, ua.u + 0x8000u, 0x07060302u);
}

__device__ __forceinline__ void gl_lds16(const void* g, void* l) {
  __builtin_amdgcn_global_load_lds(
      (const __attribute__((address_space(1))) void*)g,
      (__attribute__((address_space(3))) void*)l, 16, 0, 0);
}

// ---------------- pre-pass kernels ----------------

__global__ void cast_f32_bf16(const float* __restrict__ src, short* __restrict__ dst, int n8) {
  int i = blockIdx.x * blockDim.x + threadIdx.x;
  if (i >= n8) return;
  const float4* s4 = (const float4*)src;
  float4 a = s4[2 * i], b = s4[2 * i + 1];
  bf16x8 o;
  o[0] = f2bf(a.x); o[1] = f2bf(a.y); o[2] = f2bf(a.z); o[3] = f2bf(a.w);
  o[4] = f2bf(b.x); o[5] = f2bf(b.y); o[6] = f2bf(b.z); o[7] = f2bf(b.w);
  *(bf16x8*)&dst[8 * i] = o;
}

// src [R][Cc] fp32 (row-major) -> dst [Cc][R] bf16 (row-major), i.e. B^T layout.
__global__ void transpose_cast(const float* __restrict__ src, short* __restrict__ dst,
                               int R, int Cc) {
  __shared__ float tile[64][65];
  int tid = threadIdx.x;
  int c0 = blockIdx.x * 64;
  int r0 = blockIdx.y * 64;
  int lr = tid >> 4;           // 0..15
  int lc = (tid & 15) * 4;     // 0..60
#pragma unroll
  for (int i = 0; i < 4; i++) {
    int rr = lr + i * 16;
    float4 v = *(const float4*)&src[(size_t)(r0 + rr) * Cc + c0 + lc];
    tile[rr][lc + 0] = v.x; tile[rr][lc + 1] = v.y;
    tile[rr][lc + 2] = v.z; tile[rr][lc + 3] = v.w;
  }
  __syncthreads();
  int oc = tid >> 2;           // dst row (= src col) 0..63
  int seg = (tid & 3) * 16;    // dst col segment
  bf16x8 o0, o1;
#pragma unroll
  for (int u = 0; u < 8; u++) o0[u] = f2bf(tile[seg + u][oc]);
#pragma unroll
  for (int u = 0; u < 8; u++) o1[u] = f2bf(tile[seg + 8 + u][oc]);
  size_t base = (size_t)(c0 + oc) * R + r0 + seg;
  *(bf16x8*)&dst[base] = o0;
  *(bf16x8*)&dst[base + 8] = o1;
}

// ---------------- GEMM: C[M,N] = A[M,K] @ B[K,N], B given transposed [N,K] ----------------
// M fixed 8192 (64 m-tiles). 128x128 tile, BK=64, 256 threads, 4x4 MFMA/wave.
// XOR chunk swizzle on the staging global side -> conflict-free b128 frag reads.
// XCD m-slab: bid&7 = XCD owns 8 consecutive m-tiles (A slab stays in its L2).
// Operand swap (uniform per block): q/k/proj use MFMA(B,A) -> acc regs are
// contiguous in the output minor dim -> b64 / float4 stores.
// mode 0: QKV scatter (bf16 q/k/vT); mode 1: fp32 out.

__global__ __launch_bounds__(256, 2)
void gemm_bt_kernel(const short* __restrict__ A, const short* __restrict__ BT,
                    int N, int K, int nbx, int mode,
                    short* __restrict__ q, short* __restrict__ kk, short* __restrict__ vT,
                    float* __restrict__ f_out) {
  __shared__ short sA[128 * 64];
  __shared__ short sB[128 * 64];
  const int tid = threadIdx.x;
  const int lane = tid & 63;
  const int w = tid >> 6;
  const int quad = lane >> 4;
  const int r = lane & 15;

  const int bid = blockIdx.x;
  const int xcd = bid & 7;
  const int local = bid >> 3;
  const int mloc = local / nbx, nloc = local - mloc * nbx;
  const int bm0 = (xcd * 8 + mloc) * 128;   // 64 m-tiles, 8 per XCD
  const int bn0 = nloc * 128;

  const int wm = (w >> 1) * 64;
  const int wn = (w & 1) * 64;
  const int sel = (mode == 0) ? (bn0 >> 10) : 3;   // 0=q,1=k,2=v,3=proj
  const bool swapped = (sel != 2);

  f32x4 acc[4][4];
#pragma unroll
  for (int i = 0; i < 4; i++)
#pragma unroll
    for (int j = 0; j < 4; j++) acc[i][j] = (f32x4){0.f, 0.f, 0.f, 0.f};

  for (int kb = 0; kb < K; kb += 64) {
    __syncthreads();
#pragma unroll
    for (int j2 = 0; j2 < 4; j2++) {
      int idx = (w * 4 + j2) * 64 + lane;    // 1024 chunks of 16B per tile
      int row = idx >> 3, ch = idx & 7;
      int g = ch ^ (row & 7);                // global-side swizzle
      gl_lds16(A + (size_t)(bm0 + row) * K + kb + g * 8, (char*)sA + idx * 16);
      gl_lds16(BT + (size_t)(bn0 + row) * K + kb + g * 8, (char*)sB + idx * 16);
    }
    __syncthreads();
#pragma unroll
    for (int c = 0; c < 2; c++) {
      bf16x8 af[4], bfr[4];
#pragma unroll
      for (int i = 0; i < 4; i++) {
        const int sw = ((c << 2) + quad) ^ (r & 7);
        af[i]  = *(const bf16x8*)&sA[(wm + i * 16 + r) * 64 + sw * 8];
        bfr[i] = *(const bf16x8*)&sB[(wn + i * 16 + r) * 64 + sw * 8];
      }
      if (swapped) {
#pragma unroll
        for (int i = 0; i < 4; i++)
#pragma unroll
          for (int j = 0; j < 4; j++)
            acc[i][j] = MFMA(bfr[j], af[i], acc[i][j]);   // C^T tile
      } else {
#pragma unroll
        for (int i = 0; i < 4; i++)
#pragma unroll
          for (int j = 0; j < 4; j++)
            acc[i][j] = MFMA(af[i], bfr[j], acc[i][j]);
      }
    }
  }

  if (mode == 1) {
    // swapped: row=quad*4+reg = n (contiguous), col=r = m -> float4 stores
#pragma unroll
    for (int i = 0; i < 4; i++) {
      const int m = bm0 + wm + i * 16 + r;
#pragma unroll
      for (int j = 0; j < 4; j++) {
        const int nf = bn0 + wn + j * 16 + quad * 4;
        *(f32x4*)&f_out[(size_t)m * N + nf] = acc[i][j];
      }
    }
  } else if (sel == 2) {
    // v, unswapped: row=quad*4+reg = token t (contiguous), col=r -> n
    // vT stored [B,H,HD,T]: regs = consecutive t -> b64 store
#pragma unroll
    for (int j = 0; j < 4; j++) {
      const int n = bn0 + wn + j * 16 + r;
      const int d = n & 63, h = (n & 1023) >> 6;
#pragma unroll
      for (int i = 0; i < 4; i++) {
        const int t0 = bm0 + wm + i * 16 + quad * 4;
        const int bh = (t0 >> 11) * NH + h;
        uint2 pk = make_uint2(pkbf(acc[i][j][0], acc[i][j][1]),
                              pkbf(acc[i][j][2], acc[i][j][3]));
        *(uint2*)&vT[((size_t)bh * HD + d) * NT + (t0 & 2047)] = pk;
      }
    }
  } else {
    // q/k, swapped: regs = consecutive d -> b64 store per (i,j)
    short* dst = (sel == 0) ? q : kk;
    const float scl = (sel == 0) ? SCALE_Q : 1.0f;
#pragma unroll
    for (int i = 0; i < 4; i++) {
      const int t = bm0 + wm + i * 16 + r;
      const int bb = (t >> 11) * NH;
      const int tt = t & 2047;
#pragma unroll
      for (int j = 0; j < 4; j++) {
        const int nf = bn0 + wn + j * 16 + quad * 4;
        const int rem = nf & 1023, h = rem >> 6, d0 = rem & 63;
        uint2 pk = make_uint2(pkbf(acc[i][j][0] * scl, acc[i][j][1] * scl),
                              pkbf(acc[i][j][2] * scl, acc[i][j][3] * scl));
        *(uint2*)&dst[((size_t)(bb + h) * NT + tt) * HD + d0] = pk;
      }
    }
  }
}

// ---------------- causal flash attention (block-staged, shuffle-free) ----------------
// 1024 blocks: one 128-row band each, heavy bands first (measured better than
// uniform 512 pairing: 3 resident blocks/CU > 2 -> barrier drains overlap).
// K[128x64], V^T[64x128] staged via global_load_lds w16 + XOR swizzle.
// S^T = K @ Q^T keeps softmax lane-local; row sums via MFMA vs ones; P packed
// with v_perm. nt-outer: each K fragment read ONCE, both strips computed;
// strip-0's P goes to sP immediately, strip-1's P held in 16 regs and written
// after strip-0's PV reads (same-wave DS ops execute in order -> safe reuse).

__device__ __forceinline__ void attn_band(
    const short* __restrict__ Qb, const short* __restrict__ Kb,
    const short* __restrict__ VTb, short* __restrict__ Og,
    short* __restrict__ sK, short* __restrict__ sV, short* __restrict__ sPw,
    const int band, const int bh, const int w, const int lane) {
  const int quad = lane >> 4;
  const int r = lane & 15;
  const int q0 = band * 128 + w * 32;    // wave's 32 q-rows (2 strips)

  // Q as B-operand (n = q-row = lane&15, k contiguous d)
  bf16x8 bQ[2][2];
#pragma unroll
  for (int mi = 0; mi < 2; mi++) {
    const size_t qrow = ((size_t)q0 + mi * 16 + r) * HD;
    bQ[mi][0] = *(const bf16x8*)&Qb[qrow + quad * 8];
    bQ[mi][1] = *(const bf16x8*)&Qb[qrow + 32 + quad * 8];
  }
  bf16x8 vone;
#pragma unroll
  for (int u = 0; u < 8; u++) vone[u] = (short)0x3F80;  // bf16 1.0

  f32x4 acc[2][4];
  f32x4 lacc[2];
#pragma unroll
  for (int mi = 0; mi < 2; mi++) {
    lacc[mi] = (f32x4){0.f, 0.f, 0.f, 0.f};
#pragma unroll
    for (int dt = 0; dt < 4; dt++) acc[mi][dt] = (f32x4){0.f, 0.f, 0.f, 0.f};
  }

  for (int kt = 0; kt <= band; kt++) {
    const int kv0 = kt * 128;
    const bool diag = (kt == band);
    __syncthreads();                     // prior-tile LDS consumers done
#pragma unroll
    for (int j = 0; j < 4; j++) {
      int idx = (w * 4 + j) * 64 + lane; // 1024 chunks of 16B per tile
      int krow = idx >> 3, kch = idx & 7;
      int kg = kch ^ (krow & 7);         // global-side swizzle
      gl_lds16(Kb + (size_t)(kv0 + krow) * HD + kg * 8, (char*)sK + idx * 16);
      int vrow = idx >> 4, vch = idx & 15;
      int vg = (vch & 8) | ((vch ^ vrow) & 7);
      gl_lds16(VTb + (size_t)vrow * NT + kv0 + vg * 8, (char*)sV + idx * 16);
    }
    __syncthreads();                     // drains vmcnt(0): tiles landed

    // V fragments hoisted once per tile, reused by both strips
    bf16x8 vf[4][4];
#pragma unroll
    for (int dt = 0; dt < 4; dt++)
#pragma unroll
      for (int c = 0; c < 4; c++) {
        int ch = quad + 4 * c;
        int sw = (ch & 8) | ((ch ^ (r & 7)) & 7);
        vf[dt][c] = *(const bf16x8*)&sV[(dt * 16 + r) * 128 + sw * 8];
      }

    // QK + softmax, nt outer: K frags read once, both strips computed.
    const int nts0 = diag ? (w * 2 + 1) : 8;   // live kv subtiles, strip 0
    const int nts1 = diag ? (w * 2 + 2) : 8;   // live kv subtiles, strip 1
    uint2 pk1r[8];
#pragma unroll
    for (int nt = 0; nt < 8; nt++) {
      uint2 pk0 = make_uint2(0u, 0u);
      pk1r[nt] = make_uint2(0u, 0u);
      if (nt < nts1) {                   // wave-uniform
        const int krow = nt * 16 + r;
        const int sw0 = quad ^ (r & 7);
        bf16x8 k0 = *(const bf16x8*)&sK[krow * 64 + sw0 * 8];
        bf16x8 k1 = *(const bf16x8*)&sK[krow * 64 + (sw0 ^ 4) * 8];
        if (nt < nts0) {                 // strip 0
          f32x4 st = (f32x4){0.f, 0.f, 0.f, 0.f};
          st = MFMA(k0, bQ[0][0], st);
          st = MFMA(k1, bQ[0][1], st);
          if (diag && nt == nts0 - 1) {
            const int kvb = kv0 + nt * 16 + quad * 4;
            const int qg = q0 + r;
#pragma unroll
            for (int reg = 0; reg < 4; reg++)
              if (kvb + reg > qg) st[reg] = -1e30f;
          }
          pk0.x = pkbf(__builtin_amdgcn_exp2f(st[0]), __builtin_amdgcn_exp2f(st[1]));
          pk0.y = pkbf(__builtin_amdgcn_exp2f(st[2]), __builtin_amdgcn_exp2f(st[3]));
        }
        {                                // strip 1
          f32x4 st = (f32x4){0.f, 0.f, 0.f, 0.f};
          st = MFMA(k0, bQ[1][0], st);
          st = MFMA(k1, bQ[1][1], st);
          if (diag && nt == nts1 - 1) {
            const int kvb = kv0 + nt * 16 + quad * 4;
            const int qg = q0 + 16 + r;
#pragma unroll
            for (int reg = 0; reg < 4; reg++)
              if (kvb + reg > qg) st[reg] = -1e30f;
          }
          pk1r[nt].x = pkbf(__builtin_amdgcn_exp2f(st[0]), __builtin_amdgcn_exp2f(st[1]));
          pk1r[nt].y = pkbf(__builtin_amdgcn_exp2f(st[2]), __builtin_amdgcn_exp2f(st[3]));
        }
      }
      *(uint2*)&sPw[r * 136 + nt * 16 + quad * 4] = pk0;
    }
    __builtin_amdgcn_s_waitcnt(0xc07f);  // lgkmcnt(0); same-wave, no barrier
    // strip 0 PV
    {
      bf16x8 aP[4];
#pragma unroll
      for (int c = 0; c < 4; c++)
        aP[c] = *(const bf16x8*)&sPw[r * 136 + c * 32 + quad * 8];
#pragma unroll
      for (int c = 0; c < 4; c++)
        lacc[0] = MFMA(aP[c], vone, lacc[0]);       // l += P @ 1
#pragma unroll
      for (int dt = 0; dt < 4; dt++)
#pragma unroll
        for (int c = 0; c < 4; c++)
          acc[0][dt] = MFMA(aP[c], vf[dt][c], acc[0][dt]);
    }
    // strip 1: write held P, then PV (same-wave DS ordering protects reuse)
#pragma unroll
    for (int nt = 0; nt < 8; nt++)
      *(uint2*)&sPw[r * 136 + nt * 16 + quad * 4] = pk1r[nt];
    __builtin_amdgcn_s_waitcnt(0xc07f);  // lgkmcnt(0)
    {
      bf16x8 aP[4];
#pragma unroll
      for (int c = 0; c < 4; c++)
        aP[c] = *(const bf16x8*)&sPw[r * 136 + c * 32 + quad * 8];
#pragma unroll
      for (int c = 0; c < 4; c++)
        lacc[1] = MFMA(aP[c], vone, lacc[1]);
#pragma unroll
      for (int dt = 0; dt < 4; dt++)
#pragma unroll
        for (int c = 0; c < 4; c++)
          acc[1][dt] = MFMA(aP[c], vf[dt][c], acc[1][dt]);
    }
  }

  // epilogue: O/l, C-layout (row=quad*4+reg=q-row, col=r); token-major bf16 out
  const int b = bh >> 4, h = bh & 15;
#pragma unroll
  for (int mi = 0; mi < 2; mi++)
#pragma unroll
    for (int reg = 0; reg < 4; reg++) {
      const int trow = q0 + mi * 16 + quad * 4 + reg;
      const float inv = 1.0f / lacc[mi][reg];
      const size_t base = ((size_t)(b * NT + trow)) * NC + h * HD;
#pragma unroll
      for (int dt = 0; dt < 4; dt++)
        Og[base + dt * 16 + r] = f2bf(acc[mi][dt][reg] * inv);
    }
}

__global__ __launch_bounds__(256, 3)
void attn_kernel(const short* __restrict__ Q, const short* __restrict__ Kg,
                 const short* __restrict__ VT, short* __restrict__ Og) {
  __shared__ short sK[128 * 64];       // [kv][d], chunk-swizzled
  __shared__ short sV[64 * 128];       // [d][kv], chunk-swizzled
  __shared__ short sP[4][16 * 136];    // per-wave P strip, stride 136 (>=128+pad)
  const int tid = threadIdx.x;
  const int lane = tid & 63;
  const int w = tid >> 6;

  const int n = blockIdx.x;              // 0..1023
  const int xcd = n & 7;
  const int slot = n >> 3;               // 0..127
  const int bh = xcd * 8 + (slot & 7);   // 8 heads per XCD
  const int band = 15 - (slot >> 3);     // heavy bands dispatched first

  const short* Qb  = Q  + (size_t)bh * NT * HD;
  const short* Kb  = Kg + (size_t)bh * NT * HD;
  const short* VTb = VT + (size_t)bh * HD * NT;

  attn_band(Qb, Kb, VTb, Og, sK, sV, &sP[w][0], band, bh, w, lane);
}

// ---------------- launch ----------------

extern "C" void kernel_launch(void* const* d_in, const int* in_sizes, int n_in,
                              void* d_out, int out_size, void* d_ws, size_t ws_size,
                              hipStream_t stream) {
  const float* x     = (const float*)d_in[0];   // [B,T,C] fp32
  const float* wqkv  = (const float*)d_in[1];   // [C,3C] fp32
  const float* wproj = (const float*)d_in[2];   // [C,C] fp32
  float* out = (float*)d_out;                   // [B,T,C] fp32

  // workspace layout (bytes): 88 MB total
  char* ws = (char*)d_ws;
  short* xb  = (short*)(ws + 0);          // x bf16        16,777,216 B
  short* wqT = (short*)(ws + 16777216);   // w_qkv^T bf16   6,291,456 B
  short* wpT = (short*)(ws + 23068672);   // w_proj^T bf16  2,097,152 B
  short* q   = (short*)(ws + 25165824);   // [B,H,T,HD]    16,777,216 B
  short* kk  = (short*)(ws + 41943040);   // [B,H,T,HD]    16,777,216 B
  short* vT  = (short*)(ws + 58720256);   // [B,H,HD,T]    16,777,216 B
  short* att = (short*)(ws + 75497472);   // [B*T, C] bf16 16,777,216 B

  cast_f32_bf16<<<4096, 256, 0, stream>>>(x, xb, (NB * NT * NC) / 8);
  transpose_cast<<<dim3(48, 16), 256, 0, stream>>>(wqkv, wqT, NC, 3 * NC);
  transpose_cast<<<dim3(16, 16), 256, 0, stream>>>(wproj, wpT, NC, NC);
  // qkv = xb @ wqkv  -> scatter to q/k/vT   (1536 blocks: 8 XCD x 8m x 24n)
  gemm_bt_kernel<<<1536, 256, 0, stream>>>(xb, wqT, 3 * NC, NC, 24, 0, q, kk, vT, nullptr);
  // attention (1024 blocks: 8 XCD x 8 heads x 16 bands, heavy first)
  attn_kernel<<<1024, 256, 0, stream>>>(q, kk, vT, att);
  // out = att @ wproj  (512 blocks: 8 XCD x 8m x 8n)
  gemm_bt_kernel<<<512, 256, 0, stream>>>(att, wpT, NC, NC, 8, 1, nullptr, nullptr, nullptr, out);
}